// Round 5
// baseline (242.830 us; speedup 1.0000x reference)
//
#include <hip/hip_runtime.h>
#include <hip/hip_bf16.h>

// Problem constants
#define NB   128     // frames
#define NP   4096    // points per frame
#define NGRP 16
#define C3   512

typedef __bf16 bf16x8 __attribute__((ext_vector_type(8)));
typedef __bf16 bf16x4 __attribute__((ext_vector_type(4)));
typedef float  f32x4  __attribute__((ext_vector_type(4)));

// ws layout (bytes) — weights in MFMA A-fragment chunk order:
// chunk c holds A[m=l15][k=quad*8+j] as elem c*512 + lane*8 + j
#define WS_W1F_G 0        // 4 chunks (64ch x K32, k>=4 zero)
#define WS_W1F_L 4096
#define WS_W2F_G 8192     // 16 chunks (128ch x K64): c = (ch>>4)*2 + (k>>5)
#define WS_W2F_L 24576
#define WS_W3F_G 40960    // 128 chunks (512ch x K128): c = (ch>>4)*4 + (k>>5)
#define WS_W3F_L 172032
#define WS_GMAX  303104   // [16][512] f32

__global__ __launch_bounds__(256) void prep_kernel(
    const float* __restrict__ Wg1, const float* __restrict__ Wg2, const float* __restrict__ Wg3,
    const float* __restrict__ Wl1, const float* __restrict__ Wl2, const float* __restrict__ Wl3,
    char* __restrict__ ws) {
    const int t = blockIdx.x, tid = threadIdx.x;
    if (t == 36) {   // W1 frags (both branches) + gmax zero
        float* gmax = (float*)(ws + WS_GMAX);
        #pragma unroll
        for (int k = 0; k < 32; ++k) gmax[k * 256 + tid] = 0.0f;
        int c = tid >> 6, lane = tid & 63;
        int ch = c * 16 + (lane & 15);
        int kb = (lane >> 4) * 8;
        bf16x8 pg, pl;
        #pragma unroll
        for (int j = 0; j < 8; ++j) {
            int k = kb + j;
            pg[j] = (k < 4) ? (__bf16)Wg1[k * 64 + ch] : (__bf16)0.0f;
            pl[j] = (k < 4) ? (__bf16)Wl1[k * 64 + ch] : (__bf16)0.0f;
        }
        *(bf16x8*)((__bf16*)(ws + WS_W1F_G) + c * 512 + lane * 8) = pg;
        *(bf16x8*)((__bf16*)(ws + WS_W1F_L) + c * 512 + lane * 8) = pl;
        return;
    }
    // W2/W3 transpose-to-fragment tiles via LDS (coalesced both sides)
    __shared__ float tile[64][65];
    const float* src; __bf16* dst; int cBase, mMul, srcStride;
    if (t < 32) {       // W3 [128k][512ch]: tiles 64x64, (tk 0..1, tc 0..7) per branch
        int branch = t >> 4, rem = t & 15;
        int tk = rem >> 3, tc = rem & 7;
        src = (branch ? Wl3 : Wg3) + (size_t)(tk * 64) * 512 + tc * 64;
        dst = (__bf16*)(ws + (branch ? WS_W3F_L : WS_W3F_G));
        cBase = tc * 16 + tk * 2; mMul = 4; srcStride = 512;
    } else {            // W2 [64k][128ch]: tiles 64x64, tc 0..1 per branch
        int u = t - 32; int branch = u >> 1, tc = u & 1;
        src = (branch ? Wl2 : Wg2) + tc * 64;
        dst = (__bf16*)(ws + (branch ? WS_W2F_L : WS_W2F_G));
        cBase = tc * 8; mMul = 2; srcStride = 128;
    }
    {
        int r0 = tid >> 6, cl = tid & 63;
        #pragma unroll
        for (int p = 0; p < 16; ++p)
            tile[p * 4 + r0][cl] = src[(size_t)(p * 4 + r0) * srcStride + cl];
    }
    __syncthreads();
    int lane = tid & 63, l15 = lane & 15, q = lane >> 4;
    #pragma unroll
    for (int cc = 0; cc < 2; ++cc) {
        int pair = (tid >> 6) * 2 + cc;     // (mi,ks) 0..7
        int mi = pair >> 1, ks = pair & 1;
        bf16x8 pk;
        #pragma unroll
        for (int j = 0; j < 8; ++j) pk[j] = (__bf16)tile[ks * 32 + q * 8 + j][mi * 16 + l15];
        *(bf16x8*)(dst + (cBase + mi * mMul + ks) * 512 + lane * 8) = pk;
    }
}

// Grid (128 frames, 2 branches), 512 thr = 8 waves, block owns a whole frame
// (32 macros of 128 pts). Per macro:
//  L1 (wave-private, own 16 pts, 4 MFMA) -> h1f chunks;  barrier;
//  L2 (wave = 32ch-slice x 64pt-half, W2 reg-resident, 16 MFMA) -> h2f chunks;
//  barrier;  P2/L3 (wave = 128ch-slice x 64pt-half, W3 128 VGPR resident,
//  128 MFMA) streams h2f with lane-contiguous conflict-free reads.
// L1(m+1)/L2(m+1) are interleaved between P2(m)'s two halves (h2f dbuf).
// bias3+relu commute with max -> applied once at the end.
__global__ __launch_bounds__(512, 2) void main_kernel(
    const float* __restrict__ pc, const float* __restrict__ tt, const int* __restrict__ idx,
    const float* __restrict__ bg1, const float* __restrict__ bg2, const float* __restrict__ bg3,
    const float* __restrict__ bl1, const float* __restrict__ bl2, const float* __restrict__ bl3,
    float* __restrict__ out, char* __restrict__ ws) {
    __shared__ __align__(16) char smem[82688];
    __bf16* h2f = (__bf16*)smem;               // 2 x 16384 elems (65536 B)
    __bf16* h1f = (__bf16*)(smem + 65536);     // 8192 elems (16384 B); reused as fscr
    float*  b1s = (float*)(smem + 81920);      // 64 f32
    float*  b2s = (float*)(smem + 82176);      // 128 f32

    const int tid = threadIdx.x, lane = tid & 63, wave = tid >> 6;
    const int quad = lane >> 4, l15 = lane & 15;
    const int branch = blockIdx.y, frame = blockIdx.x;
    const int half = wave >> 2;        // pt-half for L2/L3
    const int slice = wave & 3;        // ch-slice for L2 (32ch) / L3 (128ch)

    // pc passthrough: branch-0 block copies its frame (overlaps compute)
    if (branch == 0) {
        const f32x4* ps = (const f32x4*)(pc + (size_t)frame * 3 * NP);
        f32x4* pd = (f32x4*)(out + NB * 2 * C3 + (size_t)frame * 3 * NP);
        #pragma unroll
        for (int j = 0; j < 6; ++j) pd[j * 512 + tid] = ps[j * 512 + tid];
    }

    const __bf16* w1g = (const __bf16*)(ws + (branch ? WS_W1F_L : WS_W1F_G));
    const __bf16* w2g = (const __bf16*)(ws + (branch ? WS_W2F_L : WS_W2F_G));
    const __bf16* w3g = (const __bf16*)(ws + (branch ? WS_W3F_L : WS_W3F_G));
    const float* b1 = branch ? bl1 : bg1;
    const float* b2 = branch ? bl2 : bg2;
    const float* b3 = branch ? bl3 : bg3;

    if (tid < 64)  b1s[tid] = b1[tid];
    if (tid < 128) b2s[tid] = b2[tid];

    // resident frags: W1 (16 VGPR), W2 slice (16), W3 slice (128)
    bf16x8 a1[4];
    #pragma unroll
    for (int mi = 0; mi < 4; ++mi) a1[mi] = *(const bf16x8*)(w1g + mi * 512 + lane * 8);
    bf16x8 a2[2][2];
    #pragma unroll
    for (int mi = 0; mi < 2; ++mi)
        #pragma unroll
        for (int ks = 0; ks < 2; ++ks)
            a2[mi][ks] = *(const bf16x8*)(w2g + ((slice * 2 + mi) * 2 + ks) * 512 + lane * 8);
    bf16x8 aw[8][4];
    #pragma unroll
    for (int mi = 0; mi < 8; ++mi)
        #pragma unroll
        for (int ks = 0; ks < 4; ++ks)
            aw[mi][ks] = *(const bf16x8*)(w3g + ((slice * 8 + mi) * 4 + ks) * 512 + lane * 8);

    const float tval = tt[frame];
    const f32x4 zf = {0.0f, 0.0f, 0.0f, 0.0f};
    f32x4 runmax[8];
    #pragma unroll
    for (int mi = 0; mi < 8; ++mi) runmax[mi] = (f32x4){-1e30f, -1e30f, -1e30f, -1e30f};

    const float* pcx = pc + (size_t)frame * 3 * NP;
    const int pw = wave * 16 + l15;    // this wave's L1 point within a macro

    // ---- L1: own 16 pts -> h1f chunks (chunk=(pt>>4)*2+(ch>>5))
    auto do_l1 = [&](float xx, float xy, float xz) {
        bf16x8 xb;
        #pragma unroll
        for (int j = 0; j < 8; ++j) xb[j] = (__bf16)0.0f;
        if (quad == 0) { xb[0] = (__bf16)xx; xb[1] = (__bf16)xy; xb[2] = (__bf16)xz; xb[3] = (__bf16)tval; }
        #pragma unroll
        for (int mi = 0; mi < 4; ++mi) {
            f32x4 c = __builtin_amdgcn_mfma_f32_16x16x32_bf16(a1[mi], xb, zf, 0, 0, 0);
            f32x4 bv = *(const f32x4*)(b1s + mi * 16 + quad * 4);
            bf16x4 pk;
            #pragma unroll
            for (int r = 0; r < 4; ++r) pk[r] = (__bf16)fmaxf(c[r] + bv[r], 0.0f);
            const int kq = (mi & 1) * 2 + (quad >> 1);
            *(bf16x4*)(h1f + (wave * 2 + (mi >> 1)) * 512 + kq * 128 + l15 * 8 + (quad & 1) * 4) = pk;
        }
    };
    // ---- L2: 32ch-slice x 64pt-half, K=64, reads h1f frags (contiguous) -> h2f chunks
    auto do_l2 = [&](__bf16* hbn) {
        #pragma unroll
        for (int ni = 0; ni < 4; ++ni) {
            const int p16 = half * 4 + ni;
            bf16x8 q0 = *(const bf16x8*)(h1f + (p16 * 2 + 0) * 512 + lane * 8);
            bf16x8 q1 = *(const bf16x8*)(h1f + (p16 * 2 + 1) * 512 + lane * 8);
            #pragma unroll
            for (int mi = 0; mi < 2; ++mi) {
                f32x4 c = __builtin_amdgcn_mfma_f32_16x16x32_bf16(a2[mi][0], q0, zf, 0, 0, 0);
                c = __builtin_amdgcn_mfma_f32_16x16x32_bf16(a2[mi][1], q1, c, 0, 0, 0);
                f32x4 bv = *(const f32x4*)(b2s + slice * 32 + mi * 16 + quad * 4);
                bf16x4 pk;
                #pragma unroll
                for (int r = 0; r < 4; ++r) pk[r] = (__bf16)fmaxf(c[r] + bv[r], 0.0f);
                const int kq = mi * 2 + (quad >> 1);
                *(bf16x4*)(hbn + (p16 * 4 + slice) * 512 + kq * 128 + l15 * 8 + (quad & 1) * 4) = pk;
            }
        }
    };
    // ---- P2: two point-groups (p16base, +1), 64 MFMA, conflict-free reads
    auto p2_pair = [&](const __bf16* hb, int p16base) {
        bf16x8 bhA[4], bhB[4];
        #pragma unroll
        for (int ks = 0; ks < 4; ++ks)
            bhA[ks] = *(const bf16x8*)(hb + (p16base * 4 + ks) * 512 + lane * 8);
        #pragma unroll
        for (int ks = 0; ks < 4; ++ks)
            bhB[ks] = *(const bf16x8*)(hb + ((p16base + 1) * 4 + ks) * 512 + lane * 8);
        #pragma unroll
        for (int u = 0; u < 2; ++u) {
            const bf16x8* cur = u ? bhB : bhA;
            #pragma unroll
            for (int mi = 0; mi < 8; ++mi) {
                f32x4 acc = __builtin_amdgcn_mfma_f32_16x16x32_bf16(aw[mi][0], cur[0], zf, 0, 0, 0);
                acc = __builtin_amdgcn_mfma_f32_16x16x32_bf16(aw[mi][1], cur[1], acc, 0, 0, 0);
                acc = __builtin_amdgcn_mfma_f32_16x16x32_bf16(aw[mi][2], cur[2], acc, 0, 0, 0);
                acc = __builtin_amdgcn_mfma_f32_16x16x32_bf16(aw[mi][3], cur[3], acc, 0, 0, 0);
                #pragma unroll
                for (int r = 0; r < 4; ++r) runmax[mi][r] = fmaxf(runmax[mi][r], acc[r]);
            }
        }
    };

    __syncthreads();   // b1s/b2s ready

    // prologue: macro 0 through L1+L2 into h2f buf 0
    {
        float xx = pcx[pw], xy = pcx[NP + pw], xz = pcx[2 * NP + pw];
        do_l1(xx, xy, xz);
        __syncthreads();
        do_l2(h2f);
    }

    for (int m = 0; m < 32; ++m) {
        __syncthreads();                       // h2f[m&1] ready, h1f consumed
        const __bf16* hb = h2f + (m & 1) * 16384;
        __bf16* hbn = h2f + ((m + 1) & 1) * 16384;
        const bool more = (m < 31);
        float nx = 0.f, ny = 0.f, nz = 0.f;
        if (more) {
            const int p = (m + 1) * 128 + pw;
            nx = pcx[p]; ny = pcx[NP + p]; nz = pcx[2 * NP + p];
        }
        p2_pair(hb, half * 4 + 0);             // ni 0,1 of this wave's half
        if (more) do_l1(nx, ny, nz);           // h1f safe: last read before top barrier
        __syncthreads();                       // h1f ready
        p2_pair(hb, half * 4 + 2);             // ni 2,3
        if (more) do_l2(hbn);                  // other buffer: last read in prev iter
    }

    // ---- finalize: fold 16 pt-columns, combine the two halves, bias3+relu
    __syncthreads();
    float* fscr = (float*)h1f;                 // [2 halves][512 ch]
    #pragma unroll
    for (int mi = 0; mi < 8; ++mi) {
        f32x4 v = runmax[mi];
        #pragma unroll
        for (int d = 1; d < 16; d <<= 1) {
            #pragma unroll
            for (int r = 0; r < 4; ++r) v[r] = fmaxf(v[r], __shfl_xor(v[r], d));
        }
        if (l15 == 0) {
            #pragma unroll
            for (int r = 0; r < 4; ++r)
                fscr[half * 512 + slice * 128 + mi * 16 + quad * 4 + r] = v[r];
        }
    }
    __syncthreads();
    {
        const int g = idx[frame];
        float* gmax = (float*)(ws + WS_GMAX);
        float v = fmaxf(fscr[tid], fscr[512 + tid]);
        v = fmaxf(v + b3[tid], 0.0f);
        if (branch == 0)
            atomicMax((unsigned*)(gmax + g * C3 + tid), __float_as_uint(v)); // relu>=0
        else
            out[(size_t)frame * (2 * C3) + C3 + tid] = v;
    }
}

__global__ void gather_kernel(const int* __restrict__ idx, const char* __restrict__ ws,
                              float* __restrict__ out) {
    int i = blockIdx.x * blockDim.x + threadIdx.x;   // 0..65535
    int b = i >> 9, ch = i & 511;
    const float* gmax = (const float*)(ws + WS_GMAX);
    out[b * (2 * C3) + ch] = gmax[idx[b] * C3 + ch];
}

extern "C" void kernel_launch(void* const* d_in, const int* in_sizes, int n_in,
                              void* d_out, int out_size, void* d_ws, size_t ws_size,
                              hipStream_t stream) {
    const float* pc  = (const float*)d_in[0];
    const float* tt  = (const float*)d_in[1];
    const int*   idx = (const int*)d_in[2];
    const float* Wg1 = (const float*)d_in[3];  const float* bg1 = (const float*)d_in[4];
    const float* Wg2 = (const float*)d_in[5];  const float* bg2 = (const float*)d_in[6];
    const float* Wg3 = (const float*)d_in[7];  const float* bg3 = (const float*)d_in[8];
    const float* Wl1 = (const float*)d_in[9];  const float* bl1 = (const float*)d_in[10];
    const float* Wl2 = (const float*)d_in[11]; const float* bl2 = (const float*)d_in[12];
    const float* Wl3 = (const float*)d_in[13]; const float* bl3 = (const float*)d_in[14];
    float* out = (float*)d_out;
    char*  ws  = (char*)d_ws;

    // prep: weight frag layout (LDS transpose) + gmax zero — 37 small blocks
    prep_kernel<<<37, 256, 0, stream>>>(Wg1, Wg2, Wg3, Wl1, Wl2, Wl3, ws);
    // main: 128 frames x 2 branches = 256 blocks (pc passthrough folded in)
    main_kernel<<<dim3(128, 2), 512, 0, stream>>>(pc, tt, idx, bg1, bg2, bg3,
                                                  bl1, bl2, bl3, out, ws);
    gather_kernel<<<256, 256, 0, stream>>>(idx, ws, out);
}